// Round 13
// baseline (6638.883 us; speedup 1.0000x reference)
//
#include <hip/hip_runtime.h>
#include <math.h>

#define BATCH 128
#define CCH 5
#define SEQ 512
#define UNITS 256
#define RU 512

#define ENC_N 33554432   // BATCH*SEQ*RU floats

__device__ __forceinline__ float sigmoidf_(float v) {
    return 1.0f / (1.0f + __expf(-v));
}
__device__ __forceinline__ float tanhf_(float v) {
    float e = __expf(2.0f * v);
    return 1.0f - 2.0f / (e + 1.0f);
}
__device__ __forceinline__ void astoref(float* p, float v) {
    __hip_atomic_store(p, v, __ATOMIC_RELAXED, __HIP_MEMORY_SCOPE_AGENT);
}
__device__ __forceinline__ void astorei(int* p, int v) {
    __hip_atomic_store(p, v, __ATOMIC_RELAXED, __HIP_MEMORY_SCOPE_AGENT);
}
__device__ __forceinline__ unsigned long long aloadu64(const unsigned long long* p) {
    return __hip_atomic_load(p, __ATOMIC_RELAXED, __HIP_MEMORY_SCOPE_AGENT);
}
__device__ __forceinline__ int aloadi(const int* p) {
    return __hip_atomic_load(p, __ATOMIC_RELAXED, __HIP_MEMORY_SCOPE_AGENT);
}
// read a value held in an AGPR into a VGPR (one shuttle, reused 16x)
#define AREAD(DST, SRC) \
    asm("v_accvgpr_read_b32 %0, %1" : "=v"(DST) : "a"(SRC))

// ---------------------------------------------------------------------------
// Encoder: 256 blocks = dir(2) x tile(16; 8 batches) x slice(8; 32 units).
// Weights live in AGPRs (unified budget: 128/wave at 16 waves/CU); z-core is
// quad-outer so each weight is shuttled AGPR->VGPR once per 16 FMAs.
// ---------------------------------------------------------------------------
__global__ __attribute__((amdgpu_flat_work_group_size(1024, 1024),
                          amdgpu_waves_per_eu(4, 4)))
void encoder_kernel(const float* __restrict__ x,
                    const float* __restrict__ Wf_k, const float* __restrict__ Wf_r,
                    const float* __restrict__ bf,
                    const float* __restrict__ Wb_k, const float* __restrict__ Wb_r,
                    const float* __restrict__ bb,
                    float* __restrict__ enc, float* __restrict__ h_ex,
                    int* __restrict__ flags)
{
    const int bid  = blockIdx.x;
    const int dir  = bid >> 7;
    const int tile = (bid >> 3) & 15;
    const int jsl  = bid & 7;
    const int grp  = dir * 16 + tile;
    const int bg0  = tile * 8;
    const float* __restrict__ Wk   = dir ? Wb_k : Wf_k;
    const float* __restrict__ Wr   = dir ? Wb_r : Wf_r;
    const float* __restrict__ bias = dir ? bb : bf;
    const int tid = threadIdx.x;
    const int wv  = tid >> 6;
    const int l   = tid & 63;
    const int g0 = ((l >> 5) << 8) + jsl * 32 + (l & 31);

    __shared__ float zp[16][8][128];                // 64 KB (plain, 2-way free)
    __shared__ float __align__(16) hLe[2][8][260];  // 16.6 KB (dbuf, +4 pad)
    __shared__ float zred[8][128];                  // 4 KB
    __shared__ float WkL[5][128];
    __shared__ float biasL[128];
    __shared__ unsigned char mL[8][SEQ];            // 4 KB
    __shared__ float xLe[8][8];

    // ---- one-time staging ----
    for (int i = tid; i < 2 * 8 * 260; i += 1024) ((float*)hLe)[i] = 0.0f;
    if (tid < 128) biasL[tid] = bias[((tid >> 5) << 8) + jsl * 32 + (tid & 31)];
    if (tid >= 128 && tid < 768) {
        int i = tid - 128, c = i >> 7, cl = i & 127;
        WkL[c][cl] = Wk[c * 1024 + ((cl >> 5) << 8) + jsl * 32 + (cl & 31)];
    }
    for (int i = tid; i < 8 * SEQ; i += 1024) {
        int b = i >> 9, tt = i & (SEQ - 1);
        mL[b][tt] = (x[((size_t)((bg0 + b) * CCH) * SEQ + tt) * 3 + 2] != 0.0f) ? 1 : 0;
    }
    // weights (held in AGPRs): rows 16*wv..+15, cols g0 and g0+512
    float wA[16], wB[16];
    {
        const float* wbase = Wr + (size_t)(wv * 16) * 1024 + g0;
        #pragma unroll
        for (int r = 0; r < 16; ++r) {
            wA[r] = wbase[(size_t)r * 1024];
            wB[r] = wbase[(size_t)r * 1024 + 512];
        }
    }
    float creg = 0.0f, hreg = 0.0f;   // gate-thread state (tid<256)
    __syncthreads();

    for (int t = 0; t < SEQ; ++t) {
        const int cur = t & 1;
        const int ts = dir ? (SEQ - 1 - t) : t;
        if (t > 0 && wv < 8) {
            // wave w loads slice w's output: u in [32w,+32), all 8 batches
            if (l < 4) {
                const int* fp = &flags[(grp * 8 + wv) * 32 + l];
                int guard = 0;
                while (aloadi(fp) < t && guard < (1 << 26)) {
                    __builtin_amdgcn_s_sleep(1); ++guard;
                }
            }
            int b = l >> 3, u0 = wv * 32 + (l & 7) * 4;
            const unsigned long long* hsrc = (const unsigned long long*)
                &h_ex[(size_t)(dir * 2 + ((t - 1) & 1)) * 32768
                      + (size_t)(bg0 + b) * UNITS + u0];
            unsigned long long v0 = aloadu64(hsrc);
            unsigned long long v1 = aloadu64(hsrc + 1);
            float4 hv;
            ((unsigned long long*)&hv)[0] = v0;
            ((unsigned long long*)&hv)[1] = v1;
            *(float4*)&hLe[cur][b][u0] = hv;
        }
        if (tid >= 960 && tid < 1000) {  // wave 15: x_t for the 8 batches
            int i = tid - 960, b = i / 5, c = i - b * 5;
            xLe[b][c] = x[((size_t)((bg0 + b) * CCH + c) * SEQ + ts) * 3];
        }
        __syncthreads();   // B1

        // z-core, quad-outer: 4 quads x {8 h4 loads, 8 AGPR reads, 64 FMA}
        float accA[8], accB[8];
        #pragma unroll
        for (int b = 0; b < 8; ++b) { accA[b] = 0.f; accB[b] = 0.f; }
        const float* hbase = &hLe[cur][0][wv * 16];
        #pragma unroll
        for (int q = 0; q < 4; ++q) {
            float4 h4[8];
            #pragma unroll
            for (int b = 0; b < 8; ++b)
                h4[b] = *(const float4*)(hbase + b * 260 + q * 4);
            #pragma unroll
            for (int rr = 0; rr < 4; ++rr) {
                const int r = q * 4 + rr;
                float w0, w1;
                AREAD(w0, wA[r]);
                AREAD(w1, wB[r]);
                #pragma unroll
                for (int b = 0; b < 8; ++b) {
                    float hh = (rr == 0) ? h4[b].x : (rr == 1) ? h4[b].y
                             : (rr == 2) ? h4[b].z : h4[b].w;
                    accA[b] = fmaf(hh, w0, accA[b]);
                    accB[b] = fmaf(hh, w1, accB[b]);
                }
            }
        }
        #pragma unroll
        for (int b = 0; b < 8; ++b) {
            zp[wv][b][l]      = accA[b];
            zp[wv][b][64 + l] = accB[b];
        }
        __syncthreads();   // B2

        // stage-A: 1024 threads, one (b,cl): bias + 16 slots + x@Wk
        {
            int b = tid >> 7, cl = tid & 127;
            float sum = biasL[cl];
            #pragma unroll
            for (int s = 0; s < 16; ++s) sum += zp[s][b][cl];
            #pragma unroll
            for (int c = 0; c < 5; ++c) sum = fmaf(xLe[b][c], WkL[c][cl], sum);
            zred[b][cl] = sum;
        }
        __syncthreads();   // B2b

        if (tid < 256) {   // stage-B: gates + mask + publish; per-wave sub-flag
            int b = tid >> 5, u = tid & 31;
            float zi = zred[b][u];
            float zf = zred[b][32 + u];
            float zg = zred[b][64 + u];
            float zo = zred[b][96 + u];
            float cn = sigmoidf_(zf) * creg + sigmoidf_(zi) * tanhf_(zg);
            float hn = sigmoidf_(zo) * tanhf_(cn);
            int m = mL[b][ts];
            float h2 = m ? hn : hreg;
            float c2 = m ? cn : creg;
            creg = c2; hreg = h2;
            astoref(&h_ex[(size_t)(dir * 2 + cur) * 32768
                          + (size_t)(bg0 + b) * UNITS + jsl * 32 + u], h2);
            enc[((size_t)(bg0 + b) * SEQ + ts) * RU + dir * UNITS + jsl * 32 + u] = h2;
            asm volatile("s_waitcnt vmcnt(0)" ::: "memory");
            if (l == 0) astorei(&flags[(grp * 8 + jsl) * 32 + wv], t + 1);
        }
        // no trailing barrier: hLe dbuf'd; zp/zred rewritten only after next B1/B2
    }
}

// ---------------------------------------------------------------------------
// Attention precompute (alpha constant over decoder time). One block/batch.
// ---------------------------------------------------------------------------
__global__ __launch_bounds__(256)
void attn_kernel(const float* __restrict__ enc,
                 const float* __restrict__ W_attn, const float* __restrict__ b_attn,
                 const float* __restrict__ W_dense, const float* __restrict__ b_dense,
                 const float* __restrict__ x,
                 float* __restrict__ attn_ws, float* __restrict__ hidden_ws,
                 float* __restrict__ xbuf, float* __restrict__ xconst)
{
    const int b = blockIdx.x;
    const int tid = threadIdx.x;
    const int lane = tid & 63;
    const int wv = tid >> 6;

    __shared__ float WeL[RU];
    __shared__ float scoresL[SEQ];
    __shared__ float red[256];
    __shared__ float attnL[RU];

    WeL[tid]       = W_attn[CCH + tid];
    WeL[tid + 256] = W_attn[CCH + tid + 256];
    __syncthreads();

    const float* __restrict__ encb = enc + (size_t)b * SEQ * RU;
    const float batt = b_attn[0];

    for (int s = wv; s < SEQ; s += 4) {
        const float* row = encb + (size_t)s * RU;
        float p = 0.0f;
        #pragma unroll
        for (int i = 0; i < 8; ++i) {
            int d = lane * 8 + i;
            p = fmaf(row[d], WeL[d], p);
        }
        #pragma unroll
        for (int o = 32; o; o >>= 1) p += __shfl_xor(p, o);
        if (lane == 0) scoresL[s] = p + batt;
    }
    __syncthreads();

    float m = fmaxf(scoresL[tid], scoresL[tid + 256]);
    red[tid] = m;
    __syncthreads();
    for (int st = 128; st; st >>= 1) {
        if (tid < st) red[tid] = fmaxf(red[tid], red[tid + st]);
        __syncthreads();
    }
    const float mx = red[0];
    __syncthreads();
    float e0 = __expf(scoresL[tid] - mx);
    float e1 = __expf(scoresL[tid + 256] - mx);
    red[tid] = e0 + e1;
    __syncthreads();
    for (int st = 128; st; st >>= 1) {
        if (tid < st) red[tid] += red[tid + st];
        __syncthreads();
    }
    const float sinv = 1.0f / red[0];
    __syncthreads();
    scoresL[tid]       = e0 * sinv;
    scoresL[tid + 256] = e1 * sinv;
    __syncthreads();

    float a0 = 0.0f, a1 = 0.0f;
    for (int s = 0; s < SEQ; ++s) {
        float al = scoresL[s];
        a0 = fmaf(al, encb[(size_t)s * RU + tid], a0);
        a1 = fmaf(al, encb[(size_t)s * RU + tid + 256], a1);
    }
    attn_ws[(size_t)b * RU + tid]       = a0;
    attn_ws[(size_t)b * RU + tid + 256] = a1;
    attnL[tid] = a0;
    attnL[tid + 256] = a1;
    hidden_ws[(size_t)b * RU + tid]       = encb[(size_t)(SEQ - 1) * RU + tid];
    hidden_ws[(size_t)b * RU + tid + 256] = encb[(size_t)(SEQ - 1) * RU + tid + 256];
    if (tid < CCH) xbuf[b * CCH + tid] = x[((size_t)(b * CCH + tid) * SEQ + 0) * 3];
    __syncthreads();

    if (tid < CCH) {
        float acc = b_dense[tid];
        for (int d = 0; d < RU; ++d)
            acc = fmaf(attnL[d], W_dense[(RU + d) * CCH + tid], acc);
        xconst[b * CCH + tid] = acc;
    }
}

// ---------------------------------------------------------------------------
// Decoder: 256 blocks = tile(16; 8 batches) x slice(16; 32 units).
// Weights in AGPRs, quad-outer z-core (64 shuttles/step instead of 512).
// ---------------------------------------------------------------------------
__global__ __attribute__((amdgpu_flat_work_group_size(1024, 1024),
                          amdgpu_waves_per_eu(4, 4)))
void decoder_kernel(const float* __restrict__ Wd_k, const float* __restrict__ Wd_r,
                    const float* __restrict__ bd,
                    const float* __restrict__ W_dense,
                    const float* __restrict__ attn_ws, const float* __restrict__ hidden_ws,
                    const float* __restrict__ xbuf, const float* __restrict__ xconst,
                    float* __restrict__ h_ex, int* __restrict__ flags,
                    float* __restrict__ out)
{
    const int bid  = blockIdx.x;
    const int tile = bid >> 4;
    const int jsl  = bid & 15;
    const int bg0  = tile * 8;
    const int tid  = threadIdx.x;
    const int wv   = tid >> 6;
    const int l    = tid & 63;
    const int g0 = ((l >> 5) << 9) + jsl * 32 + (l & 31);

    __shared__ float zp[16][8][128];                // 64 KB (plain)
    __shared__ float __align__(16) hL[2][8][516];   // 33 KB (dbuf, +4 pad)
    __shared__ float zred[8][128];                  // 4 KB
    __shared__ float WdL[RU * CCH];                 // 10 KB
    __shared__ float WkL[5][128];                   // 2.5 KB
    __shared__ float biasL[128];
    __shared__ float xL[8][8], xcL[8][8];

    // ---- one-time staging ----
    for (int i = tid; i < RU * CCH; i += 1024) WdL[i] = W_dense[i];
    if (tid < 128) biasL[tid] = bd[((tid >> 5) << 9) + jsl * 32 + (tid & 31)];
    if (tid >= 128 && tid < 768) {
        int i = tid - 128, c = i >> 7, cl = i & 127;
        WkL[c][cl] = Wd_k[c * 2048 + ((cl >> 5) << 9) + jsl * 32 + (cl & 31)];
    }
    if (tid < 64) {
        int b = tid >> 3, c = tid & 7;
        if (c < 5) {
            xL[b][c]  = xbuf[(bg0 + b) * CCH + c];
            xcL[b][c] = xconst[(bg0 + b) * CCH + c];
        }
    }
    {   // t=0 h from hidden_ws
        int f = tid * 4, b = f >> 9, u = f & (RU - 1);
        *(float4*)&hL[0][b][u] = *(const float4*)&hidden_ws[(size_t)(bg0 + b) * RU + u];
    }
    // att value for gate thread (b,u) in a register
    float attR = 0.0f;
    if (tid < 256)
        attR = attn_ws[(size_t)(bg0 + (tid >> 5)) * RU + jsl * 32 + (tid & 31)];
    // weights (held in AGPRs): rows 32*wv..+31, cols g0 and g0+1024
    float wA[32], wB[32];
    {
        const float* wbase = Wd_r + (size_t)(wv * 32) * 2048 + g0;
        #pragma unroll
        for (int r = 0; r < 32; ++r) {
            wA[r] = wbase[(size_t)r * 2048];
            wB[r] = wbase[(size_t)r * 2048 + 1024];
        }
    }
    __syncthreads();

    for (int t = 0; t < SEQ - 1; ++t) {
        const int cur = t & 1;
        if (t > 0) {
            // wave w loads slice w's output: u in [32w,+32), all 8 batches
            if (l < 4) {
                const int* fp = &flags[(tile * 16 + wv) * 32 + l];
                int guard = 0;
                while (aloadi(fp) < t && guard < (1 << 26)) {
                    __builtin_amdgcn_s_sleep(1); ++guard;
                }
            }
            int b = l >> 3, u0 = wv * 32 + (l & 7) * 4;
            const unsigned long long* hsrc = (const unsigned long long*)
                &h_ex[(size_t)((t - 1) & 1) * 65536 + (size_t)(bg0 + b) * RU + u0];
            unsigned long long v0 = aloadu64(hsrc);
            unsigned long long v1 = aloadu64(hsrc + 1);
            float4 hv;
            ((unsigned long long*)&hv)[0] = v0;
            ((unsigned long long*)&hv)[1] = v1;
            *(float4*)&hL[cur][b][u0] = hv;
        }
        __syncthreads();   // B1

        // x_t dense-reduce (needs only h): overlapped with z-partial phase
        if (t > 0) {
            for (int it = wv; it < 40; it += 16) {
                int bb = it / 5, c = it - bb * 5;
                float p = 0.f;
                #pragma unroll
                for (int q = 0; q < 8; ++q) {
                    int uu = l + (q << 6);
                    p = fmaf(hL[cur][bb][uu], WdL[uu * CCH + c], p);
                }
                #pragma unroll
                for (int o = 32; o; o >>= 1) p += __shfl_xor(p, o);
                if (l == 0) xL[bb][c] = p + xcL[bb][c];
            }
        }

        // z-core, quad-outer: 8 quads x {8 h4 loads, 8 AGPR reads, 64 FMA}
        float accA[8], accB[8];
        #pragma unroll
        for (int b = 0; b < 8; ++b) { accA[b] = 0.f; accB[b] = 0.f; }
        const float* hbase = &hL[cur][0][wv * 32];
        #pragma unroll
        for (int q = 0; q < 8; ++q) {
            float4 h4[8];
            #pragma unroll
            for (int b = 0; b < 8; ++b)
                h4[b] = *(const float4*)(hbase + b * 516 + q * 4);
            #pragma unroll
            for (int rr = 0; rr < 4; ++rr) {
                const int r = q * 4 + rr;
                float w0, w1;
                AREAD(w0, wA[r]);
                AREAD(w1, wB[r]);
                #pragma unroll
                for (int b = 0; b < 8; ++b) {
                    float hh = (rr == 0) ? h4[b].x : (rr == 1) ? h4[b].y
                             : (rr == 2) ? h4[b].z : h4[b].w;
                    accA[b] = fmaf(hh, w0, accA[b]);
                    accB[b] = fmaf(hh, w1, accB[b]);
                }
            }
        }
        #pragma unroll
        for (int b = 0; b < 8; ++b) {
            zp[wv][b][l]      = accA[b];
            zp[wv][b][64 + l] = accB[b];
        }
        __syncthreads();   // B2

        // stage-A: 1024 threads, one (b,cl): bias + 16 slots + x@Wk
        {
            int b = tid >> 7, cl = tid & 127;
            float sum = biasL[cl];
            #pragma unroll
            for (int s = 0; s < 16; ++s) sum += zp[s][b][cl];
            #pragma unroll
            for (int c = 0; c < 5; ++c) sum = fmaf(xL[b][c], WkL[c][cl], sum);
            zred[b][cl] = sum;
        }
        __syncthreads();   // B2b

        if (tid < 256) {   // stage-B: gates + publish h; per-wave sub-flag
            int b = tid >> 5, u = tid & 31;
            float zi = zred[b][u];
            float zf = zred[b][32 + u];
            float zg = zred[b][64 + u];
            float zo = zred[b][96 + u];
            float cn = sigmoidf_(zf) * attR + sigmoidf_(zi) * tanhf_(zg);
            float hn = sigmoidf_(zo) * tanhf_(cn);
            astoref(&h_ex[(size_t)cur * 65536
                          + (size_t)(bg0 + b) * RU + jsl * 32 + u], hn);
            asm volatile("s_waitcnt vmcnt(0)" ::: "memory");
            if (l == 0) astorei(&flags[(tile * 16 + jsl) * 32 + wv], t + 1);
        }
        // out-write off the drain path (xL stable until after next B1)
        if (t > 0 && jsl == 0 && tid >= 256 && tid < 296) {
            int i = tid - 256, bb = i / 5, c = i - bb * 5;
            out[(size_t)((bg0 + bb) * CCH + c) * (SEQ - 1) + (t - 1)] = xL[bb][c];
        }
    }

    // ---- epilogue: out[510] from h_511 (jsl==0 blocks only) ----
    if (jsl == 0) {
        const int t = SEQ - 1;          // 511
        const int cur = t & 1;          // 1
        if (l < 4) {
            const int* fp = &flags[(tile * 16 + wv) * 32 + l];
            int guard = 0;
            while (aloadi(fp) < t && guard < (1 << 26)) {
                __builtin_amdgcn_s_sleep(1); ++guard;
            }
        }
        int b = l >> 3, u0 = wv * 32 + (l & 7) * 4;
        const unsigned long long* hsrc = (const unsigned long long*)
            &h_ex[(size_t)((t - 1) & 1) * 65536 + (size_t)(bg0 + b) * RU + u0];
        unsigned long long v0 = aloadu64(hsrc);
        unsigned long long v1 = aloadu64(hsrc + 1);
        float4 hv;
        ((unsigned long long*)&hv)[0] = v0;
        ((unsigned long long*)&hv)[1] = v1;
        *(float4*)&hL[cur][b][u0] = hv;
        __syncthreads();
        for (int it = wv; it < 40; it += 16) {
            int bb = it / 5, c = it - bb * 5;
            float p = 0.f;
            #pragma unroll
            for (int q = 0; q < 8; ++q) {
                int uu = l + (q << 6);
                p = fmaf(hL[cur][bb][uu], WdL[uu * CCH + c], p);
            }
            #pragma unroll
            for (int o = 32; o; o >>= 1) p += __shfl_xor(p, o);
            if (l == 0)
                out[(size_t)((bg0 + bb) * CCH + c) * (SEQ - 1) + (t - 1)]
                    = p + xcL[bb][c];
        }
    }
}

// ---------------------------------------------------------------------------
extern "C" void kernel_launch(void* const* d_in, const int* in_sizes, int n_in,
                              void* d_out, int out_size, void* d_ws, size_t ws_size,
                              hipStream_t stream)
{
    const float* x       = (const float*)d_in[0];
    const float* Wf_k    = (const float*)d_in[1];
    const float* Wf_r    = (const float*)d_in[2];
    const float* bf      = (const float*)d_in[3];
    const float* Wb_k    = (const float*)d_in[4];
    const float* Wb_r    = (const float*)d_in[5];
    const float* bb      = (const float*)d_in[6];
    const float* Wd_k    = (const float*)d_in[7];
    const float* Wd_r    = (const float*)d_in[8];
    const float* bd      = (const float*)d_in[9];
    const float* W_attn  = (const float*)d_in[10];
    const float* b_attn  = (const float*)d_in[11];
    const float* W_dense = (const float*)d_in[12];
    const float* b_dense = (const float*)d_in[13];
    float* out = (float*)d_out;

    float* ws = (float*)d_ws;
    // persistent (attn -> decoder) region after enc
    float* enc      = ws;                          // [0, ENC_N)
    float* attn_p   = ws + ENC_N;                  // 65536 floats
    float* hidden_p = ws + ENC_N + 65536;          // 65536 floats
    float* xbuf_p   = ws + ENC_N + 131072;         // 640
    float* xconst_p = ws + ENC_N + 131712;         // 640
    // encoder-phase overlays (dead before attn_kernel writes the same region)
    float* h_ex_e   = ws + ENC_N;                  // 4 x 128 x 256 = 131072 floats
    int*   flag_e   = (int*)(ws + ENC_N + 131072); // 32grp x 8sl x 32 = 8192 ints
    // decoder-phase overlays on dead enc region
    int*   flag_d   = (int*)ws;                    // 16tile x 16sl x 32 = 8192 ints
    float* h_ex_d   = ws + 8192;                   // 2 x 128 x 512 = 131072 floats

    hipMemsetAsync(flag_e, 0, 8192 * sizeof(int), stream);
    encoder_kernel<<<256, 1024, 0, stream>>>(x, Wf_k, Wf_r, bf, Wb_k, Wb_r, bb,
                                             enc, h_ex_e, flag_e);
    attn_kernel<<<BATCH, 256, 0, stream>>>(enc, W_attn, b_attn, W_dense, b_dense, x,
                                           attn_p, hidden_p, xbuf_p, xconst_p);
    hipMemsetAsync(flag_d, 0, 8192 * sizeof(int), stream);
    decoder_kernel<<<256, 1024, 0, stream>>>(Wd_k, Wd_r, bd, W_dense,
                                             attn_p, hidden_p, xbuf_p, xconst_p,
                                             h_ex_d, flag_d, out);
}

// Round 14
// 5257.444 us; speedup vs baseline: 1.2628x; 1.2628x over previous
//
#include <hip/hip_runtime.h>
#include <math.h>

#define BATCH 128
#define CCH 5
#define SEQ 512
#define UNITS 256
#define RU 512

#define ENC_N 33554432   // BATCH*SEQ*RU floats

__device__ __forceinline__ float sigmoidf_(float v) {
    return 1.0f / (1.0f + __expf(-v));
}
__device__ __forceinline__ float tanhf_(float v) {
    float e = __expf(2.0f * v);
    return 1.0f - 2.0f / (e + 1.0f);
}
__device__ __forceinline__ void astoreu64(unsigned long long* p, unsigned long long v) {
    __hip_atomic_store(p, v, __ATOMIC_RELAXED, __HIP_MEMORY_SCOPE_AGENT);
}
__device__ __forceinline__ unsigned long long aloadu64(const unsigned long long* p) {
    return __hip_atomic_load(p, __ATOMIC_RELAXED, __HIP_MEMORY_SCOPE_AGENT);
}
__device__ __forceinline__ unsigned long long packht(unsigned tag, float h) {
    return ((unsigned long long)tag << 32) | (unsigned long long)__float_as_uint(h);
}

// ---------------------------------------------------------------------------
// Encoder: 256 blocks = dir(2) x tile(16; 8 batches) x slice(8; 32 units).
// Tagged h-exchange: (h, step-tag) in one u64; consumers spin on their own
// data words (no flags, no vmcnt drain, single L3 round trip). Wave w's
// z-core reads only the rows wave w itself loaded -> B1 eliminated.
// ---------------------------------------------------------------------------
__global__ __attribute__((amdgpu_flat_work_group_size(1024, 1024),
                          amdgpu_waves_per_eu(4, 4)))
void encoder_kernel(const float* __restrict__ x,
                    const float* __restrict__ Wf_k, const float* __restrict__ Wf_r,
                    const float* __restrict__ bf,
                    const float* __restrict__ Wb_k, const float* __restrict__ Wb_r,
                    const float* __restrict__ bb,
                    float* __restrict__ enc, unsigned long long* __restrict__ hx)
{
    const int bid  = blockIdx.x;
    const int dir  = bid >> 7;
    const int tile = (bid >> 3) & 15;
    const int jsl  = bid & 7;
    const int bg0  = tile * 8;
    const float* __restrict__ Wk   = dir ? Wb_k : Wf_k;
    const float* __restrict__ Wr   = dir ? Wb_r : Wf_r;
    const float* __restrict__ bias = dir ? bb : bf;
    const int tid = threadIdx.x;
    const int wv  = tid >> 6;
    const int l   = tid & 63;
    const int g0 = ((l >> 5) << 8) + jsl * 32 + (l & 31);

    __shared__ float zp[16][8][128];                // 64 KB (plain, 2-way free)
    __shared__ float __align__(16) hLe[2][8][260];  // 16.6 KB (dbuf, +4 pad)
    __shared__ float zred[8][128];                  // 4 KB
    __shared__ float WkL[5][128];
    __shared__ float biasL[128];
    __shared__ unsigned char mL[8][SEQ];            // 4 KB
    __shared__ float xLe[2][8][8];                  // dbuf (no B1 -> writer races gates)

    // ---- one-time staging ----
    for (int i = tid; i < 2 * 8 * 260; i += 1024) ((float*)hLe)[i] = 0.0f;
    if (tid < 128) biasL[tid] = bias[((tid >> 5) << 8) + jsl * 32 + (tid & 31)];
    if (tid >= 128 && tid < 768) {
        int i = tid - 128, c = i >> 7, cl = i & 127;
        WkL[c][cl] = Wk[c * 1024 + ((cl >> 5) << 8) + jsl * 32 + (cl & 31)];
    }
    for (int i = tid; i < 8 * SEQ; i += 1024) {
        int b = i >> 9, tt = i & (SEQ - 1);
        mL[b][tt] = (x[((size_t)((bg0 + b) * CCH) * SEQ + tt) * 3 + 2] != 0.0f) ? 1 : 0;
    }
    // weights -> registers (pinned): rows 16*wv..+15, cols g0 and g0+512
    float wr0[16], wr1[16];
    {
        const float* wbase = Wr + (size_t)(wv * 16) * 1024 + g0;
        #pragma unroll
        for (int r = 0; r < 16; ++r) {
            wr0[r] = wbase[(size_t)r * 1024];
            wr1[r] = wbase[(size_t)r * 1024 + 512];
        }
        #pragma unroll
        for (int r = 0; r < 16; ++r)
            asm volatile("" : "+v"(wr0[r]), "+v"(wr1[r]));
    }
    float creg = 0.0f, hreg = 0.0f;   // gate-thread state (tid<256)
    __syncthreads();

    for (int t = 0; t < SEQ; ++t) {
        const int cur = t & 1;
        const int ts = dir ? (SEQ - 1 - t) : t;
        if (t > 0) {
            // wave w loads its own z-core rows: u in [16w,+16), all 8 batches
            int b = l >> 3, u0 = wv * 16 + (l & 7) * 2;
            const unsigned long long* hp = hx
                + ((size_t)(dir * 2 + ((t - 1) & 1)) * 16 + tile) * 2048
                + b * 256 + u0;
            const unsigned tg = (unsigned)t;
            unsigned long long v0, v1;
            for (int it = 0;; ++it) {
                v0 = aloadu64(hp);
                v1 = aloadu64(hp + 1);
                if ((unsigned)(v0 >> 32) == tg && (unsigned)(v1 >> 32) == tg) break;
                if (it > (1 << 22)) break;
                __builtin_amdgcn_s_sleep(1);
            }
            hLe[cur][b][u0]     = __uint_as_float((unsigned)v0);
            hLe[cur][b][u0 + 1] = __uint_as_float((unsigned)v1);
        }
        if (tid >= 960 && tid < 1000) {  // wave 15: x_t for the 8 batches
            int i = tid - 960, b = i / 5, c = i - b * 5;
            xLe[cur][b][c] = x[((size_t)((bg0 + b) * CCH + c) * SEQ + ts) * 3];
        }
        // NO barrier: z-core reads only rows this wave wrote (lgkmcnt orders)

        // z-core: 8 batches x (16 rows x 2 cols) per lane
        float accA[8], accB[8];
        #pragma unroll
        for (int b = 0; b < 8; ++b) {
            float a0 = 0.f, a1 = 0.f;
            const float4* hp4 = (const float4*)&hLe[cur][b][wv * 16];
            #pragma unroll
            for (int q = 0; q < 4; ++q) {
                float4 h4 = hp4[q];
                a0 = fmaf(h4.x, wr0[4*q+0], a0); a1 = fmaf(h4.x, wr1[4*q+0], a1);
                a0 = fmaf(h4.y, wr0[4*q+1], a0); a1 = fmaf(h4.y, wr1[4*q+1], a1);
                a0 = fmaf(h4.z, wr0[4*q+2], a0); a1 = fmaf(h4.z, wr1[4*q+2], a1);
                a0 = fmaf(h4.w, wr0[4*q+3], a0); a1 = fmaf(h4.w, wr1[4*q+3], a1);
            }
            accA[b] = a0; accB[b] = a1;
        }
        #pragma unroll
        for (int b = 0; b < 8; ++b) {
            zp[wv][b][l]      = accA[b];
            zp[wv][b][64 + l] = accB[b];
        }
        __syncthreads();   // B2 (zp + hLe + xLe all visible)

        // stage-A: 1024 threads, one (b,cl): bias + 16 slots + x@Wk
        {
            int b = tid >> 7, cl = tid & 127;
            float sum = biasL[cl];
            #pragma unroll
            for (int s = 0; s < 16; ++s) sum += zp[s][b][cl];
            #pragma unroll
            for (int c = 0; c < 5; ++c) sum = fmaf(xLe[cur][b][c], WkL[c][cl], sum);
            zred[b][cl] = sum;
        }
        __syncthreads();   // B2b

        if (tid < 256) {   // stage-B: gates + mask + tagged publish
            int b = tid >> 5, u = tid & 31;
            float zi = zred[b][u];
            float zf = zred[b][32 + u];
            float zg = zred[b][64 + u];
            float zo = zred[b][96 + u];
            float cn = sigmoidf_(zf) * creg + sigmoidf_(zi) * tanhf_(zg);
            float hn = sigmoidf_(zo) * tanhf_(cn);
            int m = mL[b][ts];
            float h2 = m ? hn : hreg;
            float c2 = m ? cn : creg;
            creg = c2; hreg = h2;
            astoreu64(&hx[((size_t)(dir * 2 + cur) * 16 + tile) * 2048
                          + b * 256 + jsl * 32 + u],
                      packht((unsigned)(t + 1), h2));
            enc[((size_t)(bg0 + b) * SEQ + ts) * RU + dir * UNITS + jsl * 32 + u] = h2;
        }
        // no trailing barrier: hLe/xLe dbuf'd; zp/zred rewritten after next B2/B2b
    }
}

// ---------------------------------------------------------------------------
// Attention precompute (alpha constant over decoder time). One block/batch.
// ---------------------------------------------------------------------------
__global__ __launch_bounds__(256)
void attn_kernel(const float* __restrict__ enc,
                 const float* __restrict__ W_attn, const float* __restrict__ b_attn,
                 const float* __restrict__ W_dense, const float* __restrict__ b_dense,
                 const float* __restrict__ x,
                 float* __restrict__ attn_ws, float* __restrict__ hidden_ws,
                 float* __restrict__ xbuf, float* __restrict__ xconst)
{
    const int b = blockIdx.x;
    const int tid = threadIdx.x;
    const int lane = tid & 63;
    const int wv = tid >> 6;

    __shared__ float WeL[RU];
    __shared__ float scoresL[SEQ];
    __shared__ float red[256];
    __shared__ float attnL[RU];

    WeL[tid]       = W_attn[CCH + tid];
    WeL[tid + 256] = W_attn[CCH + tid + 256];
    __syncthreads();

    const float* __restrict__ encb = enc + (size_t)b * SEQ * RU;
    const float batt = b_attn[0];

    for (int s = wv; s < SEQ; s += 4) {
        const float* row = encb + (size_t)s * RU;
        float p = 0.0f;
        #pragma unroll
        for (int i = 0; i < 8; ++i) {
            int d = lane * 8 + i;
            p = fmaf(row[d], WeL[d], p);
        }
        #pragma unroll
        for (int o = 32; o; o >>= 1) p += __shfl_xor(p, o);
        if (lane == 0) scoresL[s] = p + batt;
    }
    __syncthreads();

    float m = fmaxf(scoresL[tid], scoresL[tid + 256]);
    red[tid] = m;
    __syncthreads();
    for (int st = 128; st; st >>= 1) {
        if (tid < st) red[tid] = fmaxf(red[tid], red[tid + st]);
        __syncthreads();
    }
    const float mx = red[0];
    __syncthreads();
    float e0 = __expf(scoresL[tid] - mx);
    float e1 = __expf(scoresL[tid + 256] - mx);
    red[tid] = e0 + e1;
    __syncthreads();
    for (int st = 128; st; st >>= 1) {
        if (tid < st) red[tid] += red[tid + st];
        __syncthreads();
    }
    const float sinv = 1.0f / red[0];
    __syncthreads();
    scoresL[tid]       = e0 * sinv;
    scoresL[tid + 256] = e1 * sinv;
    __syncthreads();

    float a0 = 0.0f, a1 = 0.0f;
    for (int s = 0; s < SEQ; ++s) {
        float al = scoresL[s];
        a0 = fmaf(al, encb[(size_t)s * RU + tid], a0);
        a1 = fmaf(al, encb[(size_t)s * RU + tid + 256], a1);
    }
    attn_ws[(size_t)b * RU + tid]       = a0;
    attn_ws[(size_t)b * RU + tid + 256] = a1;
    attnL[tid] = a0;
    attnL[tid + 256] = a1;
    hidden_ws[(size_t)b * RU + tid]       = encb[(size_t)(SEQ - 1) * RU + tid];
    hidden_ws[(size_t)b * RU + tid + 256] = encb[(size_t)(SEQ - 1) * RU + tid + 256];
    if (tid < CCH) xbuf[b * CCH + tid] = x[((size_t)(b * CCH + tid) * SEQ + 0) * 3];
    __syncthreads();

    if (tid < CCH) {
        float acc = b_dense[tid];
        for (int d = 0; d < RU; ++d)
            acc = fmaf(attnL[d], W_dense[(RU + d) * CCH + tid], acc);
        xconst[b * CCH + tid] = acc;
    }
}

// ---------------------------------------------------------------------------
// Decoder: 256 blocks = tile(16; 8 batches) x slice(16; 32 units).
// Tagged h-exchange; B1 eliminated (slice-matched self-loads); 2 barriers.
// x@Wk moved to the gate phase (dense-reduce runs between B2 and B2b).
// ---------------------------------------------------------------------------
__global__ __attribute__((amdgpu_flat_work_group_size(1024, 1024),
                          amdgpu_waves_per_eu(4, 4)))
void decoder_kernel(const float* __restrict__ Wd_k, const float* __restrict__ Wd_r,
                    const float* __restrict__ bd,
                    const float* __restrict__ W_dense,
                    const float* __restrict__ attn_ws, const float* __restrict__ hidden_ws,
                    const float* __restrict__ xbuf, const float* __restrict__ xconst,
                    unsigned long long* __restrict__ hx,
                    float* __restrict__ out)
{
    const int bid  = blockIdx.x;
    const int tile = bid >> 4;
    const int jsl  = bid & 15;
    const int bg0  = tile * 8;
    const int tid  = threadIdx.x;
    const int wv   = tid >> 6;
    const int l    = tid & 63;
    const int g0 = ((l >> 5) << 9) + jsl * 32 + (l & 31);

    __shared__ float zp[16][8][128];                // 64 KB (plain)
    __shared__ float __align__(16) hL[2][8][516];   // 33 KB (dbuf, +4 pad)
    __shared__ float zred[8][128];                  // 4 KB
    __shared__ float WdL[RU * CCH];                 // 10 KB
    __shared__ float WkL[5][128];                   // 2.5 KB
    __shared__ float biasL[128];
    __shared__ float xL[8][8], xcL[8][8];

    // ---- one-time staging ----
    for (int i = tid; i < RU * CCH; i += 1024) WdL[i] = W_dense[i];
    if (tid < 128) biasL[tid] = bd[((tid >> 5) << 9) + jsl * 32 + (tid & 31)];
    if (tid >= 128 && tid < 768) {
        int i = tid - 128, c = i >> 7, cl = i & 127;
        WkL[c][cl] = Wd_k[c * 2048 + ((cl >> 5) << 9) + jsl * 32 + (cl & 31)];
    }
    if (tid < 64) {
        int b = tid >> 3, c = tid & 7;
        if (c < 5) {
            xL[b][c]  = xbuf[(bg0 + b) * CCH + c];
            xcL[b][c] = xconst[(bg0 + b) * CCH + c];
        }
    }
    {   // t=0 h from hidden_ws
        int f = tid * 4, b = f >> 9, u = f & (RU - 1);
        *(float4*)&hL[0][b][u] = *(const float4*)&hidden_ws[(size_t)(bg0 + b) * RU + u];
    }
    float attR = 0.0f;
    if (tid < 256)
        attR = attn_ws[(size_t)(bg0 + (tid >> 5)) * RU + jsl * 32 + (tid & 31)];
    // weights -> registers (pinned): rows 32*wv..+31, cols g0 and g0+1024
    float wr0[32], wr1[32];
    {
        const float* wbase = Wd_r + (size_t)(wv * 32) * 2048 + g0;
        #pragma unroll
        for (int r = 0; r < 32; ++r) {
            wr0[r] = wbase[(size_t)r * 2048];
            wr1[r] = wbase[(size_t)r * 2048 + 1024];
        }
        #pragma unroll
        for (int r = 0; r < 32; ++r)
            asm volatile("" : "+v"(wr0[r]), "+v"(wr1[r]));
    }
    __syncthreads();

    for (int t = 0; t < SEQ - 1; ++t) {
        const int cur = t & 1;
        if (t > 0) {
            // wave w loads its own z-core rows: u in [32w,+32), all 8 batches
            int b = l >> 3, u0 = wv * 32 + (l & 7) * 4;
            const unsigned long long* hp = hx
                + ((size_t)((t - 1) & 1) * 16 + tile) * 4096 + b * 512 + u0;
            const unsigned tg = (unsigned)t;
            unsigned long long v0, v1, v2, v3;
            for (int it = 0;; ++it) {
                v0 = aloadu64(hp);     v1 = aloadu64(hp + 1);
                v2 = aloadu64(hp + 2); v3 = aloadu64(hp + 3);
                if ((unsigned)(v0 >> 32) == tg && (unsigned)(v1 >> 32) == tg &&
                    (unsigned)(v2 >> 32) == tg && (unsigned)(v3 >> 32) == tg) break;
                if (it > (1 << 22)) break;
                __builtin_amdgcn_s_sleep(1);
            }
            float4 hv;
            hv.x = __uint_as_float((unsigned)v0);
            hv.y = __uint_as_float((unsigned)v1);
            hv.z = __uint_as_float((unsigned)v2);
            hv.w = __uint_as_float((unsigned)v3);
            *(float4*)&hL[cur][b][u0] = hv;
        }
        // NO barrier: z-core reads only rows this wave wrote

        // z-core: 8 batches x (32 rows x 2 cols) per lane
        float accA[8], accB[8];
        #pragma unroll
        for (int b = 0; b < 8; ++b) {
            float a0 = 0.f, a1 = 0.f;
            const float4* hp4 = (const float4*)&hL[cur][b][wv * 32];
            #pragma unroll
            for (int q = 0; q < 8; ++q) {
                float4 h4 = hp4[q];
                a0 = fmaf(h4.x, wr0[4*q+0], a0); a1 = fmaf(h4.x, wr1[4*q+0], a1);
                a0 = fmaf(h4.y, wr0[4*q+1], a0); a1 = fmaf(h4.y, wr1[4*q+1], a1);
                a0 = fmaf(h4.z, wr0[4*q+2], a0); a1 = fmaf(h4.z, wr1[4*q+2], a1);
                a0 = fmaf(h4.w, wr0[4*q+3], a0); a1 = fmaf(h4.w, wr1[4*q+3], a1);
            }
            accA[b] = a0; accB[b] = a1;
        }
        #pragma unroll
        for (int b = 0; b < 8; ++b) {
            zp[wv][b][l]      = accA[b];
            zp[wv][b][64 + l] = accB[b];
        }
        __syncthreads();   // B2 (zp + full hL visible)

        // x_t dense-reduce (needs all h): between B2 and B2b
        if (t > 0) {
            for (int it = wv; it < 40; it += 16) {
                int bb = it / 5, c = it - bb * 5;
                float p = 0.f;
                #pragma unroll
                for (int q = 0; q < 8; ++q) {
                    int uu = l + (q << 6);
                    p = fmaf(hL[cur][bb][uu], WdL[uu * CCH + c], p);
                }
                #pragma unroll
                for (int o = 32; o; o >>= 1) p += __shfl_xor(p, o);
                if (l == 0) xL[bb][c] = p + xcL[bb][c];
            }
        }
        // stage-A: 1024 threads, one (b,cl): bias + 16 slots (x@Wk in gates)
        {
            int b = tid >> 7, cl = tid & 127;
            float sum = biasL[cl];
            #pragma unroll
            for (int s = 0; s < 16; ++s) sum += zp[s][b][cl];
            zred[b][cl] = sum;
        }
        __syncthreads();   // B2b (zred + xL visible)

        if (tid < 256) {   // stage-B: + x@Wk, gates, tagged publish
            int b = tid >> 5, u = tid & 31;
            float zi = zred[b][u];
            float zf = zred[b][32 + u];
            float zg = zred[b][64 + u];
            float zo = zred[b][96 + u];
            #pragma unroll
            for (int c = 0; c < 5; ++c) {
                float xv = xL[b][c];
                zi = fmaf(xv, WkL[c][u], zi);      zf = fmaf(xv, WkL[c][32 + u], zf);
                zg = fmaf(xv, WkL[c][64 + u], zg); zo = fmaf(xv, WkL[c][96 + u], zo);
            }
            float cn = sigmoidf_(zf) * attR + sigmoidf_(zi) * tanhf_(zg);
            float hn = sigmoidf_(zo) * tanhf_(cn);
            astoreu64(&hx[((size_t)cur * 16 + tile) * 4096 + b * 512 + jsl * 32 + u],
                      packht((unsigned)(t + 1), hn));
        }
        // out-write off the critical path (xL stable until next dense-reduce)
        if (t > 0 && jsl == 0 && tid >= 256 && tid < 296) {
            int i = tid - 256, bb = i / 5, c = i - bb * 5;
            out[(size_t)((bg0 + bb) * CCH + c) * (SEQ - 1) + (t - 1)] = xL[bb][c];
        }
        // no trailing barrier: hL dbuf'd; zp/zred rewritten after next B2/B2b
    }

    // ---- epilogue: out[510] from h_511 (jsl==0 blocks only) ----
    if (jsl == 0) {
        const int t = SEQ - 1;          // 511
        const int cur = t & 1;          // 1
        int b = l >> 3, u0 = wv * 32 + (l & 7) * 4;
        const unsigned long long* hp = hx
            + ((size_t)((t - 1) & 1) * 16 + tile) * 4096 + b * 512 + u0;
        const unsigned tg = (unsigned)t;
        unsigned long long v0, v1, v2, v3;
        for (int it = 0;; ++it) {
            v0 = aloadu64(hp);     v1 = aloadu64(hp + 1);
            v2 = aloadu64(hp + 2); v3 = aloadu64(hp + 3);
            if ((unsigned)(v0 >> 32) == tg && (unsigned)(v1 >> 32) == tg &&
                (unsigned)(v2 >> 32) == tg && (unsigned)(v3 >> 32) == tg) break;
            if (it > (1 << 22)) break;
            __builtin_amdgcn_s_sleep(1);
        }
        float4 hv;
        hv.x = __uint_as_float((unsigned)v0);
        hv.y = __uint_as_float((unsigned)v1);
        hv.z = __uint_as_float((unsigned)v2);
        hv.w = __uint_as_float((unsigned)v3);
        *(float4*)&hL[cur][b][u0] = hv;
        __syncthreads();
        for (int it = wv; it < 40; it += 16) {
            int bb = it / 5, c = it - bb * 5;
            float p = 0.f;
            #pragma unroll
            for (int q = 0; q < 8; ++q) {
                int uu = l + (q << 6);
                p = fmaf(hL[cur][bb][uu], WdL[uu * CCH + c], p);
            }
            #pragma unroll
            for (int o = 32; o; o >>= 1) p += __shfl_xor(p, o);
            if (l == 0)
                out[(size_t)((bg0 + bb) * CCH + c) * (SEQ - 1) + (t - 1)]
                    = p + xcL[bb][c];
        }
    }
}

// ---------------------------------------------------------------------------
extern "C" void kernel_launch(void* const* d_in, const int* in_sizes, int n_in,
                              void* d_out, int out_size, void* d_ws, size_t ws_size,
                              hipStream_t stream)
{
    const float* x       = (const float*)d_in[0];
    const float* Wf_k    = (const float*)d_in[1];
    const float* Wf_r    = (const float*)d_in[2];
    const float* bf      = (const float*)d_in[3];
    const float* Wb_k    = (const float*)d_in[4];
    const float* Wb_r    = (const float*)d_in[5];
    const float* bb      = (const float*)d_in[6];
    const float* Wd_k    = (const float*)d_in[7];
    const float* Wd_r    = (const float*)d_in[8];
    const float* bd      = (const float*)d_in[9];
    const float* W_attn  = (const float*)d_in[10];
    const float* b_attn  = (const float*)d_in[11];
    const float* W_dense = (const float*)d_in[12];
    const float* b_dense = (const float*)d_in[13];
    float* out = (float*)d_out;

    float* ws = (float*)d_ws;
    // persistent (attn -> decoder) region after enc
    float* enc      = ws;                          // [0, ENC_N)
    float* attn_p   = ws + ENC_N;                  // 65536 floats
    float* hidden_p = ws + ENC_N + 65536;          // 65536 floats
    float* xbuf_p   = ws + ENC_N + 131072;         // 640
    float* xconst_p = ws + ENC_N + 131712;         // 640
    // tagged h-exchange buffers (u64 pairs)
    // encoder: 2dir x 2buf x 16tile x (8b x 256u) = 131072 u64 = 1 MB,
    //   overlays the attn_p region (dead once encoder completes)
    unsigned long long* hx_e = (unsigned long long*)(ws + ENC_N);
    // decoder: 2buf x 16tile x (8b x 512u) = 131072 u64 = 1 MB,
    //   overlays dead enc region (memset AFTER attn consumed enc)
    unsigned long long* hx_d = (unsigned long long*)(ws + 8192);

    hipMemsetAsync(hx_e, 0, 131072 * sizeof(unsigned long long), stream);
    encoder_kernel<<<256, 1024, 0, stream>>>(x, Wf_k, Wf_r, bf, Wb_k, Wb_r, bb,
                                             enc, hx_e);
    attn_kernel<<<BATCH, 256, 0, stream>>>(enc, W_attn, b_attn, W_dense, b_dense, x,
                                           attn_p, hidden_p, xbuf_p, xconst_p);
    hipMemsetAsync(hx_d, 0, 131072 * sizeof(unsigned long long), stream);
    decoder_kernel<<<256, 1024, 0, stream>>>(Wd_k, Wd_r, bd, W_dense,
                                             attn_p, hidden_p, xbuf_p, xconst_p,
                                             hx_d, out);
}